// Round 9
// baseline (342.319 us; speedup 1.0000x reference)
//
#include <hip/hip_runtime.h>
#include <math.h>

#define NB 4
#define SEQ 8192
#define NT (NB*SEQ)        // 32768 tokens
#define HDIM 64
#define NST 16
#define NBLK 4
#define KCONV 16
#define DIN 128
#define PDIM 16            // head dim
#define NH 8
#define CDIM 160
#define EPROJ 296
#define CH 128             // chunk length
#define NC 64              // chunks per sequence

typedef __attribute__((ext_vector_type(8))) short short8;
typedef __attribute__((ext_vector_type(4))) float f32x4;

__device__ __forceinline__ float sigf(float x){ return 1.0f/(1.0f+__expf(-x)); }

__device__ __forceinline__ unsigned short bf16r(float f){
  unsigned int u = __float_as_uint(f);
  u = (u + 0x7fffu + ((u >> 16) & 1u)) >> 16;
  return (unsigned short)u;
}
__device__ __forceinline__ unsigned int pk_bf16(float a, float b){
  return (unsigned int)bf16r(a) | ((unsigned int)bf16r(b) << 16);
}
__device__ __forceinline__ float bf16f(unsigned short h){
  return __uint_as_float(((unsigned int)h) << 16);
}

// merged: h init (blocks 0..8191) + in_proj weight split (blocks 8192..8487)
__global__ __launch_bounds__(256) void k_init(const float* __restrict__ x, const float* __restrict__ w_in,
                                              float* __restrict__ h,
                                              const float* __restrict__ w,
                                              unsigned short* __restrict__ whi,
                                              unsigned short* __restrict__ wlo){
  int bi = blockIdx.x;
  const int HB = (NT*HDIM)/256;
  if(bi < HB){
    int i = bi*256 + threadIdx.x;
    int t = i >> 6, d = i & 63;
    h[i] = x[t]*w_in[d];
  } else {
    int i = (bi - HB)*256 + threadIdx.x;
    if(i < NBLK*EPROJ*HDIM){
      float f = w[i];
      unsigned short hi = bf16r(f);
      float fh = bf16f(hi);
      whi[i] = hi;
      wlo[i] = bf16r(f - fh);
    }
  }
}

// Fused front per (b,chunk): in-proj (split-bf16 MFMA, incl. 16-token conv halo)
// -> conv (LDS, no global round-trip) -> dt softplus -> cumsum -> S-MFMA.
// 1024 threads = 16 waves, 1 block/CU (148.5 KB LDS). zxz channel-major.
__global__ __launch_bounds__(1024) void k_front(const float* __restrict__ h,
                                                const unsigned short* __restrict__ whi,
                                                const unsigned short* __restrict__ wlo,
                                                const float* __restrict__ cw, const float* __restrict__ cb,
                                                const float* __restrict__ dtb, const float* __restrict__ alog,
                                                unsigned short* __restrict__ zxz,
                                                unsigned short* __restrict__ xbc,
                                                float* __restrict__ dt, float* __restrict__ acs,
                                                float* __restrict__ asum, float* __restrict__ S){
  __shared__ __align__(16) unsigned char smf[148480];
  // Phase A layout (h-split + conv input)
  unsigned short* Hh  = (unsigned short*)(smf);            // [144][72]
  unsigned short* Hl  = (unsigned short*)(smf + 20736);    // [144][72]
  float* zxcS         = (float*)(smf + 41472);             // [160][148] fp32, ends 136192
  // Phase B overlay (same region; all zxcS/H reads done before writes)
  unsigned short* XhT = (unsigned short*)(smf);            // [128][136]
  unsigned short* XlT = (unsigned short*)(smf + 34816);    // [128][136]
  unsigned short* BhT = (unsigned short*)(smf + 69632);    // [16][136]
  unsigned short* BlT = (unsigned short*)(smf + 73984);    // [16][136] ends 78336
  // Persistent region
  float* dtraw = (float*)(smf + 136192);                   // [8][128]
  float* dtl   = (float*)(smf + 140288);                   // [8][128]
  float* wle   = (float*)(smf + 144384);                   // [8][128]

  int bc = blockIdx.x;
  int c = bc & 63, b = bc >> 6;
  int t0 = b*SEQ + c*CH;
  int tid = threadIdx.x, lane = tid & 63, wid = tid >> 6;
  int quad = lane >> 4, lq = lane & 15;

  // ---- P0: stage h window (t0-16 .. t0+127) as split bf16 ----
#pragma unroll
  for(int k=0;k<3;k++){
    int idx = tid + k*1024;
    if(idx < 2304){
      int tok = idx >> 4;            // 0..143 window token
      int d0 = (idx & 15) * 4;
      float4 v;
      if(c == 0 && tok < 16){ v = make_float4(0.f,0.f,0.f,0.f); }
      else v = *(const float4*)(h + (size_t)(t0 - 16 + tok)*HDIM + d0);
      float vv[4] = {v.x, v.y, v.z, v.w};
      unsigned short hi4[4], lo4[4];
#pragma unroll
      for(int j=0;j<4;j++){
        unsigned short hi = bf16r(vv[j]);
        hi4[j] = hi;
        lo4[j] = bf16r(vv[j] - bf16f(hi));
      }
      uint2 ph, pl;
      ph.x = (unsigned int)hi4[0] | ((unsigned int)hi4[1] << 16);
      ph.y = (unsigned int)hi4[2] | ((unsigned int)hi4[3] << 16);
      pl.x = (unsigned int)lo4[0] | ((unsigned int)lo4[1] << 16);
      pl.y = (unsigned int)lo4[2] | ((unsigned int)lo4[3] << 16);
      *(uint2*)&Hh[tok*72 + d0] = ph;
      *(uint2*)&Hl[tok*72 + d0] = pl;
    }
  }
  __syncthreads();                   // B1: h-split visible

  // ---- P1: in-proj tiles (16 waves x ~10 tiles), weight prefetch 1 ahead ----
  {
    int L = wid;
    int tg, et;
    if(L < 152){ tg = 1 + L/19; et = L % 19; } else { tg = 0; et = 8 + (L - 152); }
    {
      int e_a = et*16 + lq;
      int ec = (e_a < EPROJ) ? e_a : (EPROJ-1);
      const unsigned short* wh = whi + (size_t)ec*HDIM + quad*8;
      const unsigned short* wl = wlo + (size_t)ec*HDIM + quad*8;
      short8 ah0 = *(const short8*)wh;
      short8 ah1 = *(const short8*)(wh + 32);
      short8 al0 = *(const short8*)wl;
      short8 al1 = *(const short8*)(wl + 32);
      while(true){
        int Ln = L + 16;
        int tgn = 0, etn = 0;
        short8 nh0 = ah0, nh1 = ah1, nl0 = al0, nl1 = al1;
        if(Ln < 162){
          if(Ln < 152){ tgn = 1 + Ln/19; etn = Ln % 19; } else { tgn = 0; etn = 8 + (Ln - 152); }
          int e_n = etn*16 + lq;
          int ecn = (e_n < EPROJ) ? e_n : (EPROJ-1);
          const unsigned short* wh2 = whi + (size_t)ecn*HDIM + quad*8;
          const unsigned short* wl2 = wlo + (size_t)ecn*HDIM + quad*8;
          nh0 = *(const short8*)wh2;
          nh1 = *(const short8*)(wh2 + 32);
          nl0 = *(const short8*)wl2;
          nl1 = *(const short8*)(wl2 + 32);
        }
        const unsigned short* hrh = Hh + (tg*16 + lq)*72 + quad*8;
        const unsigned short* hrl = Hl + (tg*16 + lq)*72 + quad*8;
        short8 xh0 = *(const short8*)hrh;
        short8 xh1 = *(const short8*)(hrh + 32);
        short8 xl0 = *(const short8*)hrl;
        short8 xl1 = *(const short8*)(hrl + 32);
        f32x4 acc = {0.f,0.f,0.f,0.f};
        acc = __builtin_amdgcn_mfma_f32_16x16x32_bf16(ah0, xh0, acc, 0, 0, 0);
        acc = __builtin_amdgcn_mfma_f32_16x16x32_bf16(ah1, xh1, acc, 0, 0, 0);
        acc = __builtin_amdgcn_mfma_f32_16x16x32_bf16(ah0, xl0, acc, 0, 0, 0);
        acc = __builtin_amdgcn_mfma_f32_16x16x32_bf16(ah1, xl1, acc, 0, 0, 0);
        acc = __builtin_amdgcn_mfma_f32_16x16x32_bf16(al0, xh0, acc, 0, 0, 0);
        acc = __builtin_amdgcn_mfma_f32_16x16x32_bf16(al1, xh1, acc, 0, 0, 0);
        if(tg >= 1){
          int tokg = t0 + (tg-1)*16 + lq;
#pragma unroll
          for(int r=0;r<4;r++){
            int e = et*16 + quad*4 + r;
            if(e < 128)        zxz[(size_t)e*NT + tokg] = bf16r(acc[r]);
            else if(e < 288)   zxcS[(e-128)*148 + tg*16 + lq] = acc[r];
            else if(e < 296)   dtraw[(e-288)*128 + (tg-1)*16 + lq] = acc[r];
          }
        } else {
#pragma unroll
          for(int r=0;r<4;r++){
            int e = et*16 + quad*4 + r;   // always in [128,288)
            zxcS[(e-128)*148 + lq] = acc[r];
          }
        }
        if(Ln >= 162) break;
        L = Ln; tg = tgn; et = etn;
        ah0 = nh0; ah1 = nh1; al0 = nl0; al1 = nl1;
      }
    }
  }
  __syncthreads();                   // B2: zxcS/dtraw complete

  // ---- P2: conv from LDS -> regs + xbc global; softplus dtraw->dtl ----
  unsigned int hiP[3][4], loP[3][4];
#pragma unroll
  for(int it=0; it<3; it++){
    int G = tid + it*1024;
    if(G < 2560){
      int ch = G >> 4, sg = (G & 15)*8;
      float buf[24];
#pragma unroll
      for(int q4=0;q4<6;q4++){
        float4 f = *(const float4*)&zxcS[ch*148 + sg + q4*4];
        buf[q4*4+0]=f.x; buf[q4*4+1]=f.y; buf[q4*4+2]=f.z; buf[q4*4+3]=f.w;
      }
      float wv[16];
#pragma unroll
      for(int k=0;k<16;k++) wv[k] = cw[ch*KCONV + k];
      float bias = cb[ch];
      unsigned short hs[8], ls[8];
#pragma unroll
      for(int s=0;s<8;s++){
        float acc = bias;
#pragma unroll
        for(int k=0;k<16;k++) acc += wv[k]*buf[s+1+k];
        float r = acc * sigf(acc);
        unsigned short hi = bf16r(r);
        hs[s] = hi;
        ls[s] = bf16r(r - bf16f(hi));
      }
      hiP[it][0] = (unsigned int)hs[0] | ((unsigned int)hs[1] << 16);
      hiP[it][1] = (unsigned int)hs[2] | ((unsigned int)hs[3] << 16);
      hiP[it][2] = (unsigned int)hs[4] | ((unsigned int)hs[5] << 16);
      hiP[it][3] = (unsigned int)hs[6] | ((unsigned int)hs[7] << 16);
      loP[it][0] = (unsigned int)ls[0] | ((unsigned int)ls[1] << 16);
      loP[it][1] = (unsigned int)ls[2] | ((unsigned int)ls[3] << 16);
      loP[it][2] = (unsigned int)ls[4] | ((unsigned int)ls[5] << 16);
      loP[it][3] = (unsigned int)ls[6] | ((unsigned int)ls[7] << 16);
      uint4 pk;
      pk.x = hiP[it][0]; pk.y = hiP[it][1]; pk.z = hiP[it][2]; pk.w = hiP[it][3];
      *(uint4*)(xbc + (size_t)ch*NT + t0 + sg) = pk;
    }
  }
  {
    int hh = tid >> 7, s = tid & 127;
    float raw = zxcS ? 0.f : 0.f;   // (no-op; keep structure)
    raw = dtraw[hh*128 + s] + dtb[hh];
    float v = (raw > 20.f) ? raw : log1pf(__expf(raw));
    dtl[hh*128 + s] = v;
    dt[(size_t)hh*NT + t0 + s] = v;
  }
  __syncthreads();                   // B3: zxcS reads done, dtl visible

  // ---- P3: X/B split tiles to LDS (overlay region); cumsum on waves 0..7 ----
#pragma unroll
  for(int it=0; it<3; it++){
    int G = tid + it*1024;
    if(G < 2560){
      int ch = G >> 4, sg = (G & 15)*8;
      if(ch < 128){
        uint4 vh; vh.x=hiP[it][0]; vh.y=hiP[it][1]; vh.z=hiP[it][2]; vh.w=hiP[it][3];
        uint4 vl; vl.x=loP[it][0]; vl.y=loP[it][1]; vl.z=loP[it][2]; vl.w=loP[it][3];
        *(uint4*)&XhT[ch*136 + sg] = vh;
        *(uint4*)&XlT[ch*136 + sg] = vl;
      } else if(ch < 144){
        uint4 vh; vh.x=hiP[it][0]; vh.y=hiP[it][1]; vh.z=hiP[it][2]; vh.w=hiP[it][3];
        uint4 vl; vl.x=loP[it][0]; vl.y=loP[it][1]; vl.z=loP[it][2]; vl.w=loP[it][3];
        *(uint4*)&BhT[(ch-128)*136 + sg] = vh;
        *(uint4*)&BlT[(ch-128)*136 + sg] = vl;
      }
    }
  }
  if(wid < 8){
    int hh = wid;
    float A = -__expf(alog[hh]);
    float2 dd = *(const float2*)&dtl[hh*128 + 2*lane];
    float d0 = dd.x, d1 = dd.y;
    float v0 = d0*A, v1 = d1*A;
    float s = v0 + v1;
    for(int off=1; off<64; off<<=1){
      float o = __shfl_up(s, off);
      if(lane >= off) s += o;
    }
    float tot = __shfl(s, 63);
    float excl = s - (v0+v1);
    float a0 = excl+v0, a1 = excl+v0+v1;
    *(float2*)&acs[(size_t)hh*NT + t0 + 2*lane] = make_float2(a0, a1);
    if(lane == 63) asum[(size_t)bc*NH + hh] = __expf(tot);  // pre-exp'd decay
    wle[hh*128 + 2*lane]   = d0*__expf(tot - a0);
    wle[hh*128 + 2*lane+1] = d1*__expf(tot - a1);
  }
  __syncthreads();                   // B4: X/B tiles + wle visible

  // ---- P4: S = (X*wle).B^T per head (waves 0..7) ----
  if(wid < 8){
    int hh = wid;
    f32x4 acc = {0.f,0.f,0.f,0.f};
#pragma unroll
    for(int kb=0;kb<4;kb++){
      int k0 = kb*32 + quad*8;
      short8 xh = *(const short8*)&XhT[(hh*16 + lq)*136 + k0];
      short8 xl = *(const short8*)&XlT[(hh*16 + lq)*136 + k0];
      float4 w0 = *(const float4*)&wle[hh*128 + k0];
      float4 w1 = *(const float4*)&wle[hh*128 + k0 + 4];
      float wv8[8] = {w0.x,w0.y,w0.z,w0.w,w1.x,w1.y,w1.z,w1.w};
      short8 ah, al;
#pragma unroll
      for(int j=0;j<8;j++){
        float xv = bf16f((unsigned short)xh[j]) + bf16f((unsigned short)xl[j]);
        float pw = xv * wv8[j];
        unsigned short hi = bf16r(pw);
        ah[j] = (short)hi;
        al[j] = (short)bf16r(pw - bf16f(hi));
      }
      short8 bh = *(const short8*)&BhT[lq*136 + k0];
      short8 bl = *(const short8*)&BlT[lq*136 + k0];
      acc = __builtin_amdgcn_mfma_f32_16x16x32_bf16(ah, bh, acc, 0, 0, 0);
      acc = __builtin_amdgcn_mfma_f32_16x16x32_bf16(ah, bl, acc, 0, 0, 0);
      acc = __builtin_amdgcn_mfma_f32_16x16x32_bf16(al, bh, acc, 0, 0, 0);
    }
    float* Sp = S + ((size_t)bc*NH + hh)*256;
#pragma unroll
    for(int r=0;r<4;r++) Sp[(quad*4 + r)*16 + lq] = acc[r];
  }
}

// Fused tail v8 per (b,chunk): 1024 threads = 16 waves.
// vs v6: k_scan ELIMINATED. During staging, waves 0..7 (one per head) compute
// prev[c] directly: closed form Sum_{k<c} (Prod_{j=k+1..c-1} e_j) S_k
// + (Prod_{j<c} e_j) init, using a 6-step __shfl_down suffix-product scan over
// the 64 chunk decay factors (NC=64 = one wave), then a weighted sum of
// L3-resident S rows straight into XbT cols 128..143. Waves 8..15 concurrently
// do all other staging. Removes 1 kernel + 2 launch gaps per layer and the
// prev round trip.
__global__ __launch_bounds__(1024) void k_tail(const unsigned short* __restrict__ xbc,
                                               const unsigned short* __restrict__ zxz,
                                               const float* __restrict__ dt, const float* __restrict__ acs,
                                               const float* __restrict__ S, const float* __restrict__ easum,
                                               const float* __restrict__ initst,
                                               const float* __restrict__ dskip,
                                               const float* __restrict__ nw, const float* __restrict__ opw,
                                               const float* __restrict__ mw, const float* __restrict__ mb,
                                               float* __restrict__ h,
                                               int last, const float* __restrict__ wout,
                                               float* __restrict__ out){
  __shared__ __align__(16) unsigned char sm[151840];
  unsigned short* Bb   = (unsigned short*)(sm);             // [128][24]
  unsigned short* Cb   = (unsigned short*)(sm + 6144);      // [128][24]
  unsigned short* XbT  = (unsigned short*)(sm + 12288);     // [128][168]
  unsigned short* P0   = (unsigned short*)(sm + 55296);     // [128][168] group0
  unsigned short* P1   = (unsigned short*)(sm + 98304);     // [128][168] group1
  float* Al  = (float*)(sm + 141312);                       // [8][128]
  float* Dtl = (float*)(sm + 145408);                       // [8][128]
  float* nwl = (float*)(sm + 149504);                       // 128
  float* mbl = (float*)(sm + 150016);                       // 64
  unsigned short* zbuf = (unsigned short*)(sm + 150272);    // 16
  float* ssl  = (float*)(sm + 150304);                      // [2][128]
  float* outb = (float*)(sm + 151328);                      // [128]
  // epilogue region reuse:
  unsigned short* Zb = XbT;                                 // [128][136] (ch-major)
  unsigned short* Wo = P0;                                  // [64][136]
  unsigned short* Wm = P0 + 64*136;                         // [64][72]
  unsigned short* Yn = P1;                                  // [128][136]
  unsigned short* Tt = XbT;                                 // [128][136] cols 0..63 (Zb dead after barrier 4)

  int bc = blockIdx.x;
  int c = bc & 63, b = bc >> 6;
  int t0 = b*SEQ + c*CH;
  int tid = threadIdx.x, lane = tid & 63, wid = tid >> 6;
  int quad = lane >> 4, lq = lane & 15;
  int hgrp = wid >> 3;                  // 0 or 1
  int wr7 = wid & 7;
  int widr = (wr7 < 4) ? wr7 : (11 - wr7);   // SIMD-balanced row-block index
  int strip = widr*16;

  // ---- staging: waves 8..15 stage LDS; waves 0..7 compute prev in-place ----
  if(wid >= 8){
    int tid2 = tid - 512;               // 0..511
#pragma unroll
    for(int k=0;k<2;k++){               // B/C: 32ch x 128, uint2 loads
      int i = tid2 + k*512;             // 0..1023
      int ch = i >> 5;
      int s4 = (i & 31) * 4;
      uint2 xu = *(const uint2*)&xbc[(size_t)(DIN+ch)*NT + t0 + s4];
      unsigned short v0 = (unsigned short)(xu.x & 0xffffu);
      unsigned short v1 = (unsigned short)(xu.x >> 16);
      unsigned short v2 = (unsigned short)(xu.y & 0xffffu);
      unsigned short v3 = (unsigned short)(xu.y >> 16);
      unsigned short* dst = (ch < 16) ? Bb : Cb;
      int cc2 = (ch < 16) ? ch : (ch - 16);
      dst[(s4+0)*24 + cc2] = v0;
      dst[(s4+1)*24 + cc2] = v1;
      dst[(s4+2)*24 + cc2] = v2;
      dst[(s4+3)*24 + cc2] = v3;
    }
#pragma unroll
    for(int k=0;k<8;k++){               // X*dt: 128 x 128
      int fi = tid2 + k*512;            // 0..4095
      int p = fi >> 5, s4 = fi & 31;
      uint2 xu = *(const uint2*)&xbc[(size_t)p*NT + t0 + s4*4];
      float4 dv = *(const float4*)&dt[(size_t)(p>>4)*NT + t0 + s4*4];
      float x0 = bf16f((unsigned short)(xu.x & 0xffffu));
      float x1 = bf16f((unsigned short)(xu.x >> 16));
      float x2 = bf16f((unsigned short)(xu.y & 0xffffu));
      float x3 = bf16f((unsigned short)(xu.y >> 16));
      *(unsigned int*)&XbT[p*168 + s4*4]   = pk_bf16(x0*dv.x, x1*dv.y);
      *(unsigned int*)&XbT[p*168 + s4*4+2] = pk_bf16(x2*dv.z, x3*dv.w);
    }
#pragma unroll
    for(int k=0;k<3;k++){               // XbT pad 144..167 (1536 uints)
      int idx = tid2 + k*512;
      int p = idx / 12, cc2 = idx - p*12;
      *(unsigned int*)&XbT[p*168 + 144 + 2*cc2] = 0u;
    }
#pragma unroll
    for(int k=0;k<2;k++){               // Al / Dtl
      int idx = tid2 + k*512;
      int hh = idx >> 7, s = idx & 127;
      Al[hh*128+s]  = acs[(size_t)hh*NT + t0 + s];
      Dtl[hh*128+s] = dt[(size_t)hh*NT + t0 + s];
    }
    if(tid2 < 128) nwl[tid2] = nw[tid2];
    else if(tid2 < 192) mbl[tid2-128] = mb[tid2-128];
    else if(tid2 < 208) zbuf[tid2-192] = 0;
  } else {
    // ---- prev computation, one wave per head hh = wid ----
    int hh = wid;
    // lane j holds chunk-j decay e_j (1.0 for j >= c)
    float vj = (lane < c) ? easum[((size_t)(b*NC) + lane)*NH + hh] : 1.0f;
    // inclusive suffix product s_j = prod_{i>=j} v_i (6-step butterfly)
    float s = vj;
#pragma unroll
    for(int off=1; off<64; off<<=1){
      float o = __shfl_down(s, off);
      if(lane + off < 64) s *= o;
    }
    float wk = __shfl_down(s, 1);       // lane k: prod_{j=k+1..c-1} e_j
    if(lane == 63) wk = 1.0f;
    float winit = __shfl(s, 0);         // prod_{j=0..c-1} e_j
    const size_t cs = (size_t)NH*256;
    const float* Sp0 = S + (((size_t)(b*NC))*NH + hh)*256 + lane;
    const float* ip = initst + hh*256 + lane;
    float a0 = winit * ip[0];
    float a1 = winit * ip[64];
    float a2 = winit * ip[128];
    float a3 = winit * ip[192];
    int k = 0;
    for(; k+1 < c; k += 2){
      float w0 = __shfl(wk, k), w1 = __shfl(wk, k+1);
      const float* rp0 = Sp0 + (size_t)k*cs;
      const float* rp1 = rp0 + cs;
      a0 += w0*rp0[0];   a1 += w0*rp0[64];  a2 += w0*rp0[128]; a3 += w0*rp0[192];
      a0 += w1*rp1[0];   a1 += w1*rp1[64];  a2 += w1*rp1[128]; a3 += w1*rp1[192];
    }
    if(k < c){
      float w0 = __shfl(wk, k);
      const float* rp0 = Sp0 + (size_t)k*cs;
      a0 += w0*rp0[0];   a1 += w0*rp0[64];  a2 += w0*rp0[128]; a3 += w0*rp0[192];
    }
    float av[4] = {a0, a1, a2, a3};
#pragma unroll
    for(int m=0;m<4;m++){
      int el = m*64 + lane;
      XbT[(hh*16 + (el>>4))*168 + 128 + (el & 15)] = bf16r(av[m]);
    }
  }
  // zero pad cols 144..167 + static causal upper-triangle of own group's P strip rows
  {
    unsigned short* Pgz = hgrp ? P1 : P0;
#pragma unroll
    for(int k=0;k<3;k++){
      int idx = lane + k*64;            // 0..191
      int rr = idx / 12, cc2 = idx - rr*12;
      *(unsigned int*)&Pgz[(strip+rr)*168 + 144 + 2*cc2] = 0u;
    }
    int zc0 = (widr+1)*16;              // first fully-masked col
    int nu  = (7 - widr)*8;             // uints per row to zero
    for(int u = lane>>4; u < nu; u += 4){
      *(unsigned int*)&Pgz[(strip+(lane&15))*168 + zc0 + 2*u] = 0u;
    }
  }
  __syncthreads();                      // (1) staging visible

  // ---- score: S = C.B^T, kept in registers; only causal blocks nt<=widr ----
  short8 afr;
  {
    int row = strip + lq;
    const unsigned short* ap = (quad < 2) ? &Cb[row*24 + quad*8] : zbuf;
    afr = *(const short8*)ap;
  }
  f32x4 sc[8];
#pragma unroll
  for(int nt=0;nt<8;nt++){
    f32x4 acc = {0.f,0.f,0.f,0.f};
    if(nt <= widr){
      const unsigned short* bp = (quad < 2) ? &Bb[(nt*16+lq)*24 + quad*8] : zbuf;
      short8 bfr = *(const short8*)bp;
      acc = __builtin_amdgcn_mfma_f32_16x16x32_bf16(afr, bfr, acc, 0, 0, 0);
    }
    sc[nt] = acc;
  }

  // ---- head loop: 4 heads per group, barrier-free (strip-private) ----
  unsigned short* Pg = hgrp ? P1 : P0;
  f32x4 accv[4];
  for(int j=0;j<4;j++){
    int hh2 = hgrp*4 + j;
    const float* Alh = Al + hh2*128;
    float alr[4];
#pragma unroll
    for(int r=0;r<4;r++) alr[r] = Alh[strip + quad*4 + r];
#pragma unroll
    for(int nt=0;nt<8;nt++){
      if(nt <= widr){
        int col = nt*16 + lq;
        float alc = Alh[col];
#pragma unroll
        for(int r=0;r<4;r++){
          int row = strip + quad*4 + r;
          float p = sc[nt][r] * __expf(alr[r] - alc);
          p = (col <= row) ? p : 0.f;
          Pg[row*168 + col] = bf16r(p);
        }
      }
    }
    {
      int n = lane & 15, rg = lane >> 4;
#pragma unroll
      for(int rr=0;rr<4;rr++){
        int row = strip + rg*4 + rr;
        float ea = __expf(Alh[row]);
        Pg[row*168 + 128 + n] = bf16r(bf16f(Cb[row*24+n]) * ea);
      }
    }
    f32x4 acc2 = {0.f,0.f,0.f,0.f};
#pragma unroll
    for(int ks=0;ks<5;ks++){
      short8 bfr = *(const short8*)&XbT[(hh2*16+lq)*168 + ks*32 + quad*8];
      short8 af  = *(const short8*)&Pg[(strip+lq)*168 + ks*32 + quad*8];
      acc2 = __builtin_amdgcn_mfma_f32_16x16x32_bf16(af, bfr, acc2, 0, 0, 0);
    }
    const float* Dth = Dtl + hh2*128;
    float Dk = dskip[hh2];
#pragma unroll
    for(int r=0;r<4;r++){
      int l = strip + quad*4 + r;
      float xdt = bf16f(XbT[(hh2*16+lq)*168 + l]);
      float dtv = fmaxf(Dth[l], 1e-30f);
      acc2[r] += Dk * xdt * __frcp_rn(dtv);
    }
    accv[j] = acc2;
  }
  __syncthreads();   // (2) WAR: all reads of XbT/P done before overwrite

  // ---- stage z (XbT region), Wo/Wm (P0 region) ----
#pragma unroll
  for(int k=0;k<4;k++){
    int fi = tid + k*1024;
    int p = fi >> 5, s4 = fi & 31;
    uint2 zu = *(const uint2*)&zxz[(size_t)p*NT + t0 + s4*4];
    *(unsigned int*)&Zb[p*136 + s4*4]   = zu.x;
    *(unsigned int*)&Zb[p*136 + s4*4+2] = zu.y;
  }
#pragma unroll
  for(int k=0;k<2;k++){
    int fi = tid + k*1024;
    int n = fi >> 5, k4 = fi & 31;
    float4 wv = *(const float4*)&opw[(size_t)n*DIN + k4*4];
    *(unsigned int*)&Wo[n*136 + k4*4]   = pk_bf16(wv.x, wv.y);
    *(unsigned int*)&Wo[n*136 + k4*4+2] = pk_bf16(wv.z, wv.w);
  }
  {
    int fi = tid;                       // 0..1023
    int n = fi >> 4, k4 = fi & 15;
    float4 wv = *(const float4*)&mw[(size_t)n*HDIM + k4*4];
    *(unsigned int*)&Wm[n*72 + k4*4]   = pk_bf16(wv.x, wv.y);
    *(unsigned int*)&Wm[n*72 + k4*4+2] = pk_bf16(wv.z, wv.w);
  }
  __syncthreads();   // (3) Zb/Wo/Wm visible

  // ---- gate by silu(z), partial sum-of-squares, write Yn = y*nw (bf16) ----
  float part[4] = {0.f,0.f,0.f,0.f};
#pragma unroll
  for(int j=0;j<4;j++){
    int ch = (hgrp*4+j)*16 + lq;
    float nwv = nwl[ch];
#pragma unroll
    for(int r=0;r<4;r++){
      int l = strip + quad*4 + r;
      float zv = bf16f(Zb[ch*136 + l]);
      float g = zv * sigf(zv);
      float yv = accv[j][r] * g;
      part[r] += yv*yv;
      Yn[l*136 + ch] = bf16r(yv * nwv);
    }
  }
#pragma unroll
  for(int r=0;r<4;r++){
    part[r] += __shfl_xor(part[r],1); part[r] += __shfl_xor(part[r],2);
    part[r] += __shfl_xor(part[r],4); part[r] += __shfl_xor(part[r],8);
  }
  if(lq == 0){
#pragma unroll
    for(int r=0;r<4;r++) ssl[hgrp*128 + strip + quad*4 + r] = part[r];
  }
  __syncthreads();   // (4) Yn complete (both groups), ssl complete; Zb dead

  // ---- rms, out_proj (group computes 2 output nt), scale, softsign -> Tt ----
  float rms_[4];
#pragma unroll
  for(int r=0;r<4;r++){
    int l = strip + quad*4 + r;
    rms_[r] = rsqrtf((ssl[l] + ssl[128+l])*(1.0f/128.0f) + 1e-5f);
  }
  short8 afk[4];
#pragma unroll
  for(int ks=0;ks<4;ks++) afk[ks] = *(const short8*)&Yn[(strip+lq)*136 + ks*32 + quad*8];
  f32x4 aco[2];
#pragma unroll
  for(int ntl=0;ntl<2;ntl++){ aco[ntl] = (f32x4){0.f,0.f,0.f,0.f}; }
#pragma unroll
  for(int ntl=0;ntl<2;ntl++){
    int nt = hgrp*2 + ntl;
#pragma unroll
    for(int ks=0;ks<4;ks++){
      short8 bfr = *(const short8*)&Wo[(nt*16+lq)*136 + ks*32 + quad*8];
      aco[ntl] = __builtin_amdgcn_mfma_f32_16x16x32_bf16(afk[ks], bfr, aco[ntl], 0, 0, 0);
    }
  }
  // Tt lives in region 1 (Zb, dead since barrier 4) -> no WAR barrier needed here
#pragma unroll
  for(int ntl=0;ntl<2;ntl++){
    int nt = hgrp*2 + ntl;
#pragma unroll
    for(int r=0;r<4;r++){
      int l = strip + quad*4 + r;
      float o = aco[ntl][r] * rms_[r];
      Tt[l*136 + nt*16+lq] = bf16r(o * rsqrtf(1.0f + o*o));
    }
  }
  __syncthreads();   // (6) Tt complete (both groups' cols)

  // ---- mlp: group computes 2 output nt ----
  f32x4 acm[2];
#pragma unroll
  for(int ntl=0;ntl<2;ntl++){ acm[ntl] = (f32x4){0.f,0.f,0.f,0.f}; }
#pragma unroll
  for(int ks=0;ks<2;ks++){
    short8 af = *(const short8*)&Tt[(strip+lq)*136 + ks*32 + quad*8];
#pragma unroll
    for(int ntl=0;ntl<2;ntl++){
      int nt = hgrp*2 + ntl;
      short8 bfr = *(const short8*)&Wm[(nt*16+lq)*72 + ks*32 + quad*8];
      acm[ntl] = __builtin_amdgcn_mfma_f32_16x16x32_bf16(af, bfr, acm[ntl], 0, 0, 0);
    }
  }
  // ---- residual / final output ----
  if(!last){
#pragma unroll
    for(int ntl=0;ntl<2;ntl++){
      int nt = hgrp*2 + ntl;
#pragma unroll
      for(int r=0;r<4;r++){
        int l = strip + quad*4 + r;
        int d = nt*16 + lq;
        size_t gi = (size_t)(t0+l)*HDIM + d;
        h[gi] += acm[ntl][r] + mbl[d];
      }
    }
  } else {
    float ps[4] = {0.f,0.f,0.f,0.f};
#pragma unroll
    for(int ntl=0;ntl<2;ntl++){
      int nt = hgrp*2 + ntl;
      int d = nt*16 + lq;
      float wo = wout[d];
      float bias = mbl[d];
#pragma unroll
      for(int r=0;r<4;r++){
        int l = strip + quad*4 + r;
        size_t gi = (size_t)(t0+l)*HDIM + d;
        float hn = h[gi] + acm[ntl][r] + bias;
        ps[r] += hn * wo;
      }
    }
#pragma unroll
    for(int r=0;r<4;r++){
      ps[r] += __shfl_xor(ps[r],1); ps[r] += __shfl_xor(ps[r],2);
      ps[r] += __shfl_xor(ps[r],4); ps[r] += __shfl_xor(ps[r],8);
    }
    if(hgrp == 1 && lq == 0){
#pragma unroll
      for(int r=0;r<4;r++) outb[strip + quad*4 + r] = ps[r];
    }
    __syncthreads();
    if(hgrp == 0 && lq == 0){
#pragma unroll
      for(int r=0;r<4;r++){
        int l = strip + quad*4 + r;
        out[t0 + l] = ps[r] + outb[l];
      }
    }
  }
}

extern "C" void kernel_launch(void* const* d_in, const int* in_sizes, int n_in,
                              void* d_out, int out_size, void* d_ws, size_t ws_size,
                              hipStream_t stream){
  const float* x          = (const float*)d_in[0];
  const float* w_in       = (const float*)d_in[1];
  const float* w_out      = (const float*)d_in[2];
  const float* in_proj_w  = (const float*)d_in[3];
  const float* conv_w     = (const float*)d_in[4];
  const float* conv_b     = (const float*)d_in[5];
  const float* dt_bias    = (const float*)d_in[6];
  const float* A_log      = (const float*)d_in[7];
  const float* D_skip     = (const float*)d_in[8];
  const float* init_st    = (const float*)d_in[9];
  const float* norm_w     = (const float*)d_in[10];
  const float* out_proj_w = (const float*)d_in[11];
  const float* mlp_w      = (const float*)d_in[12];
  const float* mlp_b      = (const float*)d_in[13];
  float* out = (float*)d_out;

  float* ws = (float*)d_ws;
  float* h    = ws; ws += (size_t)NT*HDIM;
  unsigned short* zxz = (unsigned short*)ws; ws += (size_t)(128*NT)/2;   // bf16 z (channel-major)
  unsigned short* xbc = (unsigned short*)ws; ws += (size_t)(CDIM*NT)/2;  // bf16 conv out
  float* dt   = ws; ws += (size_t)NH*NT;
  float* acs  = ws; ws += (size_t)NH*NT;
  float* asum = ws; ws += (size_t)NB*NC*NH;                              // exp(chunk A-sum)
  float* S    = ws; ws += (size_t)NB*NC*NH*256;
  unsigned short* whi = (unsigned short*)ws; ws += (size_t)(NBLK*EPROJ*HDIM)/2;
  unsigned short* wlo = (unsigned short*)ws; ws += (size_t)(NBLK*EPROJ*HDIM)/2;

  k_init<<<(NT*HDIM)/256 + (NBLK*EPROJ*HDIM)/256, 256, 0, stream>>>(x, w_in, h, in_proj_w, whi, wlo);
  for(int i=0;i<NBLK;i++){
    k_front<<<NB*NC, 1024, 0, stream>>>(h, whi + (size_t)i*EPROJ*HDIM, wlo + (size_t)i*EPROJ*HDIM,
                                        conv_w + i*CDIM*KCONV, conv_b + i*CDIM,
                                        dt_bias + i*NH, A_log + i*NH,
                                        zxz, xbc, dt, acs, asum, S);
    k_tail  <<<NB*NC, 1024, 0, stream>>>(xbc, zxz, dt, acs, S, asum, init_st + i*NH*256,
                                         D_skip + i*NH,
                                         norm_w + i*DIN, out_proj_w + i*HDIM*DIN,
                                         mlp_w + i*HDIM*HDIM, mlp_b + i*HDIM, h,
                                         (i == NBLK-1) ? 1 : 0, w_out, out);
  }
}

// Round 10
// 329.531 us; speedup vs baseline: 1.0388x; 1.0388x over previous
//
#include <hip/hip_runtime.h>
#include <math.h>

#define NB 4
#define SEQ 8192
#define NT (NB*SEQ)        // 32768 tokens
#define HDIM 64
#define NST 16
#define NBLK 4
#define KCONV 16
#define DIN 128
#define PDIM 16            // head dim
#define NH 8
#define CDIM 160
#define EPROJ 296
#define CH 128             // chunk length
#define NC 64              // chunks per sequence

typedef __attribute__((ext_vector_type(8))) short short8;
typedef __attribute__((ext_vector_type(4))) float f32x4;

__device__ __forceinline__ float sigf(float x){ return 1.0f/(1.0f+__expf(-x)); }

__device__ __forceinline__ unsigned short bf16r(float f){
  unsigned int u = __float_as_uint(f);
  u = (u + 0x7fffu + ((u >> 16) & 1u)) >> 16;
  return (unsigned short)u;
}
__device__ __forceinline__ unsigned int pk_bf16(float a, float b){
  return (unsigned int)bf16r(a) | ((unsigned int)bf16r(b) << 16);
}
__device__ __forceinline__ float bf16f(unsigned short h){
  return __uint_as_float(((unsigned int)h) << 16);
}

// merged: h init (blocks 0..8191) + in_proj weight split (blocks 8192..8487)
__global__ __launch_bounds__(256) void k_init(const float* __restrict__ x, const float* __restrict__ w_in,
                                              float* __restrict__ h,
                                              const float* __restrict__ w,
                                              unsigned short* __restrict__ whi,
                                              unsigned short* __restrict__ wlo){
  int bi = blockIdx.x;
  const int HB = (NT*HDIM)/256;
  if(bi < HB){
    int i = bi*256 + threadIdx.x;
    int t = i >> 6, d = i & 63;
    h[i] = x[t]*w_in[d];
  } else {
    int i = (bi - HB)*256 + threadIdx.x;
    if(i < NBLK*EPROJ*HDIM){
      float f = w[i];
      unsigned short hi = bf16r(f);
      float fh = bf16f(hi);
      whi[i] = hi;
      wlo[i] = bf16r(f - fh);
    }
  }
}

// Fused front per (b,chunk): in-proj (split-bf16 MFMA, incl. 16-token conv halo)
// -> conv (LDS, no global round-trip) -> dt softplus -> cumsum -> S-MFMA.
// 1024 threads = 16 waves, 1 block/CU (148.5 KB LDS). zxz channel-major.
__global__ __launch_bounds__(1024) void k_front(const float* __restrict__ h,
                                                const unsigned short* __restrict__ whi,
                                                const unsigned short* __restrict__ wlo,
                                                const float* __restrict__ cw, const float* __restrict__ cb,
                                                const float* __restrict__ dtb, const float* __restrict__ alog,
                                                unsigned short* __restrict__ zxz,
                                                unsigned short* __restrict__ xbc,
                                                float* __restrict__ dt, float* __restrict__ acs,
                                                float* __restrict__ asum, float* __restrict__ S){
  __shared__ __align__(16) unsigned char smf[148480];
  // Phase A layout (h-split + conv input)
  unsigned short* Hh  = (unsigned short*)(smf);            // [144][72]
  unsigned short* Hl  = (unsigned short*)(smf + 20736);    // [144][72]
  float* zxcS         = (float*)(smf + 41472);             // [160][148] fp32, ends 136192
  // Phase B overlay (same region; all zxcS/H reads done before writes)
  unsigned short* XhT = (unsigned short*)(smf);            // [128][136]
  unsigned short* XlT = (unsigned short*)(smf + 34816);    // [128][136]
  unsigned short* BhT = (unsigned short*)(smf + 69632);    // [16][136]
  unsigned short* BlT = (unsigned short*)(smf + 73984);    // [16][136] ends 78336
  // Persistent region
  float* dtraw = (float*)(smf + 136192);                   // [8][128]
  float* dtl   = (float*)(smf + 140288);                   // [8][128]
  float* wle   = (float*)(smf + 144384);                   // [8][128]

  int bc = blockIdx.x;
  int c = bc & 63, b = bc >> 6;
  int t0 = b*SEQ + c*CH;
  int tid = threadIdx.x, lane = tid & 63, wid = tid >> 6;
  int quad = lane >> 4, lq = lane & 15;

  // ---- P0: stage h window (t0-16 .. t0+127) as split bf16 ----
#pragma unroll
  for(int k=0;k<3;k++){
    int idx = tid + k*1024;
    if(idx < 2304){
      int tok = idx >> 4;            // 0..143 window token
      int d0 = (idx & 15) * 4;
      float4 v;
      if(c == 0 && tok < 16){ v = make_float4(0.f,0.f,0.f,0.f); }
      else v = *(const float4*)(h + (size_t)(t0 - 16 + tok)*HDIM + d0);
      float vv[4] = {v.x, v.y, v.z, v.w};
      unsigned short hi4[4], lo4[4];
#pragma unroll
      for(int j=0;j<4;j++){
        unsigned short hi = bf16r(vv[j]);
        hi4[j] = hi;
        lo4[j] = bf16r(vv[j] - bf16f(hi));
      }
      uint2 ph, pl;
      ph.x = (unsigned int)hi4[0] | ((unsigned int)hi4[1] << 16);
      ph.y = (unsigned int)hi4[2] | ((unsigned int)hi4[3] << 16);
      pl.x = (unsigned int)lo4[0] | ((unsigned int)lo4[1] << 16);
      pl.y = (unsigned int)lo4[2] | ((unsigned int)lo4[3] << 16);
      *(uint2*)&Hh[tok*72 + d0] = ph;
      *(uint2*)&Hl[tok*72 + d0] = pl;
    }
  }
  __syncthreads();                   // B1: h-split visible

  // ---- P1: in-proj tiles (16 waves x ~10 tiles), weight prefetch 1 ahead ----
  {
    int L = wid;
    int tg, et;
    if(L < 152){ tg = 1 + L/19; et = L % 19; } else { tg = 0; et = 8 + (L - 152); }
    {
      int e_a = et*16 + lq;
      int ec = (e_a < EPROJ) ? e_a : (EPROJ-1);
      const unsigned short* wh = whi + (size_t)ec*HDIM + quad*8;
      const unsigned short* wl = wlo + (size_t)ec*HDIM + quad*8;
      short8 ah0 = *(const short8*)wh;
      short8 ah1 = *(const short8*)(wh + 32);
      short8 al0 = *(const short8*)wl;
      short8 al1 = *(const short8*)(wl + 32);
      while(true){
        int Ln = L + 16;
        int tgn = 0, etn = 0;
        short8 nh0 = ah0, nh1 = ah1, nl0 = al0, nl1 = al1;
        if(Ln < 162){
          if(Ln < 152){ tgn = 1 + Ln/19; etn = Ln % 19; } else { tgn = 0; etn = 8 + (Ln - 152); }
          int e_n = etn*16 + lq;
          int ecn = (e_n < EPROJ) ? e_n : (EPROJ-1);
          const unsigned short* wh2 = whi + (size_t)ecn*HDIM + quad*8;
          const unsigned short* wl2 = wlo + (size_t)ecn*HDIM + quad*8;
          nh0 = *(const short8*)wh2;
          nh1 = *(const short8*)(wh2 + 32);
          nl0 = *(const short8*)wl2;
          nl1 = *(const short8*)(wl2 + 32);
        }
        const unsigned short* hrh = Hh + (tg*16 + lq)*72 + quad*8;
        const unsigned short* hrl = Hl + (tg*16 + lq)*72 + quad*8;
        short8 xh0 = *(const short8*)hrh;
        short8 xh1 = *(const short8*)(hrh + 32);
        short8 xl0 = *(const short8*)hrl;
        short8 xl1 = *(const short8*)(hrl + 32);
        f32x4 acc = {0.f,0.f,0.f,0.f};
        acc = __builtin_amdgcn_mfma_f32_16x16x32_bf16(ah0, xh0, acc, 0, 0, 0);
        acc = __builtin_amdgcn_mfma_f32_16x16x32_bf16(ah1, xh1, acc, 0, 0, 0);
        acc = __builtin_amdgcn_mfma_f32_16x16x32_bf16(ah0, xl0, acc, 0, 0, 0);
        acc = __builtin_amdgcn_mfma_f32_16x16x32_bf16(ah1, xl1, acc, 0, 0, 0);
        acc = __builtin_amdgcn_mfma_f32_16x16x32_bf16(al0, xh0, acc, 0, 0, 0);
        acc = __builtin_amdgcn_mfma_f32_16x16x32_bf16(al1, xh1, acc, 0, 0, 0);
        if(tg >= 1){
          int tokg = t0 + (tg-1)*16 + lq;
#pragma unroll
          for(int r=0;r<4;r++){
            int e = et*16 + quad*4 + r;
            if(e < 128)        zxz[(size_t)e*NT + tokg] = bf16r(acc[r]);
            else if(e < 288)   zxcS[(e-128)*148 + tg*16 + lq] = acc[r];
            else if(e < 296)   dtraw[(e-288)*128 + (tg-1)*16 + lq] = acc[r];
          }
        } else {
#pragma unroll
          for(int r=0;r<4;r++){
            int e = et*16 + quad*4 + r;   // always in [128,288)
            zxcS[(e-128)*148 + lq] = acc[r];
          }
        }
        if(Ln >= 162) break;
        L = Ln; tg = tgn; et = etn;
        ah0 = nh0; ah1 = nh1; al0 = nl0; al1 = nl1;
      }
    }
  }
  __syncthreads();                   // B2: zxcS/dtraw complete

  // ---- P2: conv from LDS -> regs + xbc global; softplus dtraw->dtl ----
  unsigned int hiP[3][4], loP[3][4];
#pragma unroll
  for(int it=0; it<3; it++){
    int G = tid + it*1024;
    if(G < 2560){
      int ch = G >> 4, sg = (G & 15)*8;
      float buf[24];
#pragma unroll
      for(int q4=0;q4<6;q4++){
        float4 f = *(const float4*)&zxcS[ch*148 + sg + q4*4];
        buf[q4*4+0]=f.x; buf[q4*4+1]=f.y; buf[q4*4+2]=f.z; buf[q4*4+3]=f.w;
      }
      float wv[16];
#pragma unroll
      for(int k=0;k<16;k++) wv[k] = cw[ch*KCONV + k];
      float bias = cb[ch];
      unsigned short hs[8], ls[8];
#pragma unroll
      for(int s=0;s<8;s++){
        float acc = bias;
#pragma unroll
        for(int k=0;k<16;k++) acc += wv[k]*buf[s+1+k];
        float r = acc * sigf(acc);
        unsigned short hi = bf16r(r);
        hs[s] = hi;
        ls[s] = bf16r(r - bf16f(hi));
      }
      hiP[it][0] = (unsigned int)hs[0] | ((unsigned int)hs[1] << 16);
      hiP[it][1] = (unsigned int)hs[2] | ((unsigned int)hs[3] << 16);
      hiP[it][2] = (unsigned int)hs[4] | ((unsigned int)hs[5] << 16);
      hiP[it][3] = (unsigned int)hs[6] | ((unsigned int)hs[7] << 16);
      loP[it][0] = (unsigned int)ls[0] | ((unsigned int)ls[1] << 16);
      loP[it][1] = (unsigned int)ls[2] | ((unsigned int)ls[3] << 16);
      loP[it][2] = (unsigned int)ls[4] | ((unsigned int)ls[5] << 16);
      loP[it][3] = (unsigned int)ls[6] | ((unsigned int)ls[7] << 16);
      uint4 pk;
      pk.x = hiP[it][0]; pk.y = hiP[it][1]; pk.z = hiP[it][2]; pk.w = hiP[it][3];
      *(uint4*)(xbc + (size_t)ch*NT + t0 + sg) = pk;
    }
  }
  {
    int hh = tid >> 7, s = tid & 127;
    float raw = dtraw[hh*128 + s] + dtb[hh];
    float v = (raw > 20.f) ? raw : log1pf(__expf(raw));
    dtl[hh*128 + s] = v;
    dt[(size_t)hh*NT + t0 + s] = v;
  }
  __syncthreads();                   // B3: zxcS reads done, dtl visible

  // ---- P3: X/B split tiles to LDS (overlay region); cumsum on waves 0..7 ----
#pragma unroll
  for(int it=0; it<3; it++){
    int G = tid + it*1024;
    if(G < 2560){
      int ch = G >> 4, sg = (G & 15)*8;
      if(ch < 128){
        uint4 vh; vh.x=hiP[it][0]; vh.y=hiP[it][1]; vh.z=hiP[it][2]; vh.w=hiP[it][3];
        uint4 vl; vl.x=loP[it][0]; vl.y=loP[it][1]; vl.z=loP[it][2]; vl.w=loP[it][3];
        *(uint4*)&XhT[ch*136 + sg] = vh;
        *(uint4*)&XlT[ch*136 + sg] = vl;
      } else if(ch < 144){
        uint4 vh; vh.x=hiP[it][0]; vh.y=hiP[it][1]; vh.z=hiP[it][2]; vh.w=hiP[it][3];
        uint4 vl; vl.x=loP[it][0]; vl.y=loP[it][1]; vl.z=loP[it][2]; vl.w=loP[it][3];
        *(uint4*)&BhT[(ch-128)*136 + sg] = vh;
        *(uint4*)&BlT[(ch-128)*136 + sg] = vl;
      }
    }
  }
  if(wid < 8){
    int hh = wid;
    float A = -__expf(alog[hh]);
    float2 dd = *(const float2*)&dtl[hh*128 + 2*lane];
    float d0 = dd.x, d1 = dd.y;
    float v0 = d0*A, v1 = d1*A;
    float s = v0 + v1;
    for(int off=1; off<64; off<<=1){
      float o = __shfl_up(s, off);
      if(lane >= off) s += o;
    }
    float tot = __shfl(s, 63);
    float excl = s - (v0+v1);
    float a0 = excl+v0, a1 = excl+v0+v1;
    *(float2*)&acs[(size_t)hh*NT + t0 + 2*lane] = make_float2(a0, a1);
    if(lane == 63) asum[(size_t)bc*NH + hh] = __expf(tot);  // pre-exp'd for scan
    wle[hh*128 + 2*lane]   = d0*__expf(tot - a0);
    wle[hh*128 + 2*lane+1] = d1*__expf(tot - a1);
  }
  __syncthreads();                   // B4: X/B tiles + wle visible

  // ---- P4: S = (X*wle).B^T per head (waves 0..7) ----
  if(wid < 8){
    int hh = wid;
    f32x4 acc = {0.f,0.f,0.f,0.f};
#pragma unroll
    for(int kb=0;kb<4;kb++){
      int k0 = kb*32 + quad*8;
      short8 xh = *(const short8*)&XhT[(hh*16 + lq)*136 + k0];
      short8 xl = *(const short8*)&XlT[(hh*16 + lq)*136 + k0];
      float4 w0 = *(const float4*)&wle[hh*128 + k0];
      float4 w1 = *(const float4*)&wle[hh*128 + k0 + 4];
      float wv8[8] = {w0.x,w0.y,w0.z,w0.w,w1.x,w1.y,w1.z,w1.w};
      short8 ah, al;
#pragma unroll
      for(int j=0;j<8;j++){
        float xv = bf16f((unsigned short)xh[j]) + bf16f((unsigned short)xl[j]);
        float pw = xv * wv8[j];
        unsigned short hi = bf16r(pw);
        ah[j] = (short)hi;
        al[j] = (short)bf16r(pw - bf16f(hi));
      }
      short8 bh = *(const short8*)&BhT[lq*136 + k0];
      short8 bl = *(const short8*)&BlT[lq*136 + k0];
      acc = __builtin_amdgcn_mfma_f32_16x16x32_bf16(ah, bh, acc, 0, 0, 0);
      acc = __builtin_amdgcn_mfma_f32_16x16x32_bf16(ah, bl, acc, 0, 0, 0);
      acc = __builtin_amdgcn_mfma_f32_16x16x32_bf16(al, bh, acc, 0, 0, 0);
    }
    float* Sp = S + ((size_t)bc*NH + hh)*256;
#pragma unroll
    for(int r=0;r<4;r++) Sp[(quad*4 + r)*16 + lq] = acc[r];
  }
}

// sequential inter-chunk scan; decay factors pre-exp'd (k_front) and preloaded
// into registers up front -> serial chain is 64 dependent FMAs only.
__global__ __launch_bounds__(64) void k_scan(const float* __restrict__ S, const float* __restrict__ easum,
                                             const float* __restrict__ init, float* __restrict__ prev){
  int q  = blockIdx.x & 3;
  int hh = (blockIdx.x >> 2) & 7;
  int b  = blockIdx.x >> 5;
  int el = q*64 + threadIdx.x;
  const size_t cs = (size_t)NH*256;
  const float* Sp = S + ((size_t)(b*NC)*NH + hh)*256 + el;
  float* Pp = prev + ((size_t)(b*NC)*NH + hh)*256 + el;
  const float* ap = easum + (size_t)(b*NC)*NH + hh;
  float e[NC];
#pragma unroll
  for(int c=0;c<NC;c++) e[c] = ap[(size_t)c*NH];   // wave-uniform, off-chain
  float r = init[hh*256 + el];
  float s0 = Sp[0], s1 = Sp[cs], s2 = Sp[2*cs], s3 = Sp[3*cs];
#pragma unroll
  for(int c=0;c<NC;c+=4){
    Pp[(size_t)c*cs] = r;
    r = e[c]*r + s0;
    s0 = (c+4 < NC) ? Sp[(size_t)(c+4)*cs] : 0.f;
    Pp[(size_t)(c+1)*cs] = r;
    r = e[c+1]*r + s1;
    s1 = (c+5 < NC) ? Sp[(size_t)(c+5)*cs] : 0.f;
    Pp[(size_t)(c+2)*cs] = r;
    r = e[c+2]*r + s2;
    s2 = (c+6 < NC) ? Sp[(size_t)(c+6)*cs] : 0.f;
    Pp[(size_t)(c+3)*cs] = r;
    r = e[c+3]*r + s3;
    s3 = (c+7 < NC) ? Sp[(size_t)(c+7)*cs] : 0.f;
  }
}

// Fused tail v6 per (b,chunk): 1024 threads = 16 waves.
// Causal-triangle skip; SIMD-balanced strip map. Tt relocated to region 1
// (Zb dead after barrier 4) -> one fewer barrier; B/C staging vectorized.
__global__ __launch_bounds__(1024) void k_tail(const unsigned short* __restrict__ xbc,
                                               const unsigned short* __restrict__ zxz,
                                               const float* __restrict__ dt, const float* __restrict__ acs,
                                               const float* __restrict__ prev, const float* __restrict__ dskip,
                                               const float* __restrict__ nw, const float* __restrict__ opw,
                                               const float* __restrict__ mw, const float* __restrict__ mb,
                                               float* __restrict__ h,
                                               int last, const float* __restrict__ wout,
                                               float* __restrict__ out){
  __shared__ __align__(16) unsigned char sm[151840];
  unsigned short* Bb   = (unsigned short*)(sm);             // [128][24]
  unsigned short* Cb   = (unsigned short*)(sm + 6144);      // [128][24]
  unsigned short* XbT  = (unsigned short*)(sm + 12288);     // [128][168]
  unsigned short* P0   = (unsigned short*)(sm + 55296);     // [128][168] group0
  unsigned short* P1   = (unsigned short*)(sm + 98304);     // [128][168] group1
  float* Al  = (float*)(sm + 141312);                       // [8][128]
  float* Dtl = (float*)(sm + 145408);                       // [8][128]
  float* nwl = (float*)(sm + 149504);                       // 128
  float* mbl = (float*)(sm + 150016);                       // 64
  unsigned short* zbuf = (unsigned short*)(sm + 150272);    // 16
  float* ssl  = (float*)(sm + 150304);                      // [2][128]
  float* outb = (float*)(sm + 151328);                      // [128]
  // epilogue region reuse:
  unsigned short* Zb = XbT;                                 // [128][136] (ch-major)
  unsigned short* Wo = P0;                                  // [64][136]
  unsigned short* Wm = P0 + 64*136;                         // [64][72]
  unsigned short* Yn = P1;                                  // [128][136]
  unsigned short* Tt = XbT;                                 // [128][136] cols 0..63 (Zb dead after barrier 4)

  int bc = blockIdx.x;
  int c = bc & 63, b = bc >> 6;
  int t0 = b*SEQ + c*CH;
  int tid = threadIdx.x, lane = tid & 63, wid = tid >> 6;
  int quad = lane >> 4, lq = lane & 15;
  int hgrp = wid >> 3;                  // 0 or 1
  int wr7 = wid & 7;
  int widr = (wr7 < 4) ? wr7 : (11 - wr7);   // SIMD-balanced row-block index
  int strip = widr*16;

  // ---- staging (1024 threads) ----
  {                                     // B/C: 32ch x 128, one uint2/thread
    int ch = tid >> 5;                  // 0..31
    int s4 = (tid & 31) * 4;
    uint2 xu = *(const uint2*)&xbc[(size_t)(DIN+ch)*NT + t0 + s4];
    unsigned short v0 = (unsigned short)(xu.x & 0xffffu);
    unsigned short v1 = (unsigned short)(xu.x >> 16);
    unsigned short v2 = (unsigned short)(xu.y & 0xffffu);
    unsigned short v3 = (unsigned short)(xu.y >> 16);
    unsigned short* dst = (ch < 16) ? Bb : Cb;
    int cc = (ch < 16) ? ch : (ch - 16);
    dst[(s4+0)*24 + cc] = v0;
    dst[(s4+1)*24 + cc] = v1;
    dst[(s4+2)*24 + cc] = v2;
    dst[(s4+3)*24 + cc] = v3;
  }
#pragma unroll
  for(int k=0;k<4;k++){                 // X*dt: 128 x 128
    int fi = tid + k*1024;
    int p = fi >> 5, s4 = fi & 31;
    uint2 xu = *(const uint2*)&xbc[(size_t)p*NT + t0 + s4*4];
    float4 dv = *(const float4*)&dt[(size_t)(p>>4)*NT + t0 + s4*4];
    float x0 = bf16f((unsigned short)(xu.x & 0xffffu));
    float x1 = bf16f((unsigned short)(xu.x >> 16));
    float x2 = bf16f((unsigned short)(xu.y & 0xffffu));
    float x3 = bf16f((unsigned short)(xu.y >> 16));
    *(unsigned int*)&XbT[p*168 + s4*4]   = pk_bf16(x0*dv.x, x1*dv.y);
    *(unsigned int*)&XbT[p*168 + s4*4+2] = pk_bf16(x2*dv.z, x3*dv.w);
  }
#pragma unroll
  for(int k=0;k<2;k++){                 // prev ext
    int idx = tid + k*1024;
    int hh = idx >> 8, rest = idx & 255;
    int p = rest >> 4, n = rest & 15;
    XbT[(hh*16+p)*168 + 128 + n] = bf16r(prev[((size_t)bc*NH + hh)*256 + rest]);
  }
#pragma unroll
  for(int k=0;k<2;k++){                 // XbT pad 144..167
    int idx = tid + k*1024;
    if(idx < 1536){
      int p = idx / 12, cc = idx - p*12;
      *(unsigned int*)&XbT[p*168 + 144 + 2*cc] = 0u;
    }
  }
  {                                     // Al / Dtl
    int hh = tid >> 7, s = tid & 127;
    Al[hh*128+s]  = acs[(size_t)hh*NT + t0 + s];
    Dtl[hh*128+s] = dt[(size_t)hh*NT + t0 + s];
  }
  if(tid < 128) nwl[tid] = nw[tid];
  else if(tid < 192) mbl[tid-128] = mb[tid-128];
  else if(tid < 208) zbuf[tid-192] = 0;
  // zero pad cols 144..167 + static causal upper-triangle of own group's P strip rows
  {
    unsigned short* Pgz = hgrp ? P1 : P0;
#pragma unroll
    for(int k=0;k<3;k++){
      int idx = lane + k*64;            // 0..191
      int rr = idx / 12, cc = idx - rr*12;
      *(unsigned int*)&Pgz[(strip+rr)*168 + 144 + 2*cc] = 0u;
    }
    int zc0 = (widr+1)*16;              // first fully-masked col
    int nu  = (7 - widr)*8;             // uints per row to zero
    for(int u = lane>>4; u < nu; u += 4){
      *(unsigned int*)&Pgz[(strip+(lane&15))*168 + zc0 + 2*u] = 0u;
    }
  }
  __syncthreads();                      // (1) staging visible

  // ---- score: S = C.B^T, kept in registers; only causal blocks nt<=widr ----
  short8 afr;
  {
    int row = strip + lq;
    const unsigned short* ap = (quad < 2) ? &Cb[row*24 + quad*8] : zbuf;
    afr = *(const short8*)ap;
  }
  f32x4 sc[8];
#pragma unroll
  for(int nt=0;nt<8;nt++){
    f32x4 acc = {0.f,0.f,0.f,0.f};
    if(nt <= widr){
      const unsigned short* bp = (quad < 2) ? &Bb[(nt*16+lq)*24 + quad*8] : zbuf;
      short8 bfr = *(const short8*)bp;
      acc = __builtin_amdgcn_mfma_f32_16x16x32_bf16(afr, bfr, acc, 0, 0, 0);
    }
    sc[nt] = acc;
  }

  // ---- head loop: 4 heads per group, barrier-free (strip-private) ----
  unsigned short* Pg = hgrp ? P1 : P0;
  f32x4 accv[4];
  for(int j=0;j<4;j++){
    int hh2 = hgrp*4 + j;
    const float* Alh = Al + hh2*128;
    float alr[4];
#pragma unroll
    for(int r=0;r<4;r++) alr[r] = Alh[strip + quad*4 + r];
#pragma unroll
    for(int nt=0;nt<8;nt++){
      if(nt <= widr){
        int col = nt*16 + lq;
        float alc = Alh[col];
#pragma unroll
        for(int r=0;r<4;r++){
          int row = strip + quad*4 + r;
          float p = sc[nt][r] * __expf(alr[r] - alc);
          p = (col <= row) ? p : 0.f;
          Pg[row*168 + col] = bf16r(p);
        }
      }
    }
    {
      int n = lane & 15, rg = lane >> 4;
#pragma unroll
      for(int rr=0;rr<4;rr++){
        int row = strip + rg*4 + rr;
        float ea = __expf(Alh[row]);
        Pg[row*168 + 128 + n] = bf16r(bf16f(Cb[row*24+n]) * ea);
      }
    }
    f32x4 acc2 = {0.f,0.f,0.f,0.f};
#pragma unroll
    for(int ks=0;ks<5;ks++){
      short8 bfr = *(const short8*)&XbT[(hh2*16+lq)*168 + ks*32 + quad*8];
      short8 af  = *(const short8*)&Pg[(strip+lq)*168 + ks*32 + quad*8];
      acc2 = __builtin_amdgcn_mfma_f32_16x16x32_bf16(af, bfr, acc2, 0, 0, 0);
    }
    const float* Dth = Dtl + hh2*128;
    float Dk = dskip[hh2];
#pragma unroll
    for(int r=0;r<4;r++){
      int l = strip + quad*4 + r;
      float xdt = bf16f(XbT[(hh2*16+lq)*168 + l]);
      float dtv = fmaxf(Dth[l], 1e-30f);
      acc2[r] += Dk * xdt * __frcp_rn(dtv);
    }
    accv[j] = acc2;
  }
  __syncthreads();   // (2) WAR: all reads of XbT/P done before overwrite

  // ---- stage z (XbT region), Wo/Wm (P0 region) ----
#pragma unroll
  for(int k=0;k<4;k++){
    int fi = tid + k*1024;
    int p = fi >> 5, s4 = fi & 31;
    uint2 zu = *(const uint2*)&zxz[(size_t)p*NT + t0 + s4*4];
    *(unsigned int*)&Zb[p*136 + s4*4]   = zu.x;
    *(unsigned int*)&Zb[p*136 + s4*4+2] = zu.y;
  }
#pragma unroll
  for(int k=0;k<2;k++){
    int fi = tid + k*1024;
    int n = fi >> 5, k4 = fi & 31;
    float4 wv = *(const float4*)&opw[(size_t)n*DIN + k4*4];
    *(unsigned int*)&Wo[n*136 + k4*4]   = pk_bf16(wv.x, wv.y);
    *(unsigned int*)&Wo[n*136 + k4*4+2] = pk_bf16(wv.z, wv.w);
  }
  {
    int fi = tid;                       // 0..1023
    int n = fi >> 4, k4 = fi & 15;
    float4 wv = *(const float4*)&mw[(size_t)n*HDIM + k4*4];
    *(unsigned int*)&Wm[n*72 + k4*4]   = pk_bf16(wv.x, wv.y);
    *(unsigned int*)&Wm[n*72 + k4*4+2] = pk_bf16(wv.z, wv.w);
  }
  __syncthreads();   // (3) Zb/Wo/Wm visible

  // ---- gate by silu(z), partial sum-of-squares, write Yn = y*nw (bf16) ----
  float part[4] = {0.f,0.f,0.f,0.f};
#pragma unroll
  for(int j=0;j<4;j++){
    int ch = (hgrp*4+j)*16 + lq;
    float nwv = nwl[ch];
#pragma unroll
    for(int r=0;r<4;r++){
      int l = strip + quad*4 + r;
      float zv = bf16f(Zb[ch*136 + l]);
      float g = zv * sigf(zv);
      float yv = accv[j][r] * g;
      part[r] += yv*yv;
      Yn[l*136 + ch] = bf16r(yv * nwv);
    }
  }
#pragma unroll
  for(int r=0;r<4;r++){
    part[r] += __shfl_xor(part[r],1); part[r] += __shfl_xor(part[r],2);
    part[r] += __shfl_xor(part[r],4); part[r] += __shfl_xor(part[r],8);
  }
  if(lq == 0){
#pragma unroll
    for(int r=0;r<4;r++) ssl[hgrp*128 + strip + quad*4 + r] = part[r];
  }
  __syncthreads();   // (4) Yn complete (both groups), ssl complete; Zb dead

  // ---- rms, out_proj (group computes 2 output nt), scale, softsign -> Tt ----
  float rms_[4];
#pragma unroll
  for(int r=0;r<4;r++){
    int l = strip + quad*4 + r;
    rms_[r] = rsqrtf((ssl[l] + ssl[128+l])*(1.0f/128.0f) + 1e-5f);
  }
  short8 afk[4];
#pragma unroll
  for(int ks=0;ks<4;ks++) afk[ks] = *(const short8*)&Yn[(strip+lq)*136 + ks*32 + quad*8];
  f32x4 aco[2];
#pragma unroll
  for(int ntl=0;ntl<2;ntl++){ aco[ntl] = (f32x4){0.f,0.f,0.f,0.f}; }
#pragma unroll
  for(int ntl=0;ntl<2;ntl++){
    int nt = hgrp*2 + ntl;
#pragma unroll
    for(int ks=0;ks<4;ks++){
      short8 bfr = *(const short8*)&Wo[(nt*16+lq)*136 + ks*32 + quad*8];
      aco[ntl] = __builtin_amdgcn_mfma_f32_16x16x32_bf16(afk[ks], bfr, aco[ntl], 0, 0, 0);
    }
  }
  // Tt lives in region 1 (Zb, dead since barrier 4) -> no WAR barrier needed here
#pragma unroll
  for(int ntl=0;ntl<2;ntl++){
    int nt = hgrp*2 + ntl;
#pragma unroll
    for(int r=0;r<4;r++){
      int l = strip + quad*4 + r;
      float o = aco[ntl][r] * rms_[r];
      Tt[l*136 + nt*16+lq] = bf16r(o * rsqrtf(1.0f + o*o));
    }
  }
  __syncthreads();   // (6) Tt complete (both groups' cols)

  // ---- mlp: group computes 2 output nt ----
  f32x4 acm[2];
#pragma unroll
  for(int ntl=0;ntl<2;ntl++){ acm[ntl] = (f32x4){0.f,0.f,0.f,0.f}; }
#pragma unroll
  for(int ks=0;ks<2;ks++){
    short8 af = *(const short8*)&Tt[(strip+lq)*136 + ks*32 + quad*8];
#pragma unroll
    for(int ntl=0;ntl<2;ntl++){
      int nt = hgrp*2 + ntl;
      short8 bfr = *(const short8*)&Wm[(nt*16+lq)*72 + ks*32 + quad*8];
      acm[ntl] = __builtin_amdgcn_mfma_f32_16x16x32_bf16(af, bfr, acm[ntl], 0, 0, 0);
    }
  }
  // ---- residual / final output ----
  if(!last){
#pragma unroll
    for(int ntl=0;ntl<2;ntl++){
      int nt = hgrp*2 + ntl;
#pragma unroll
      for(int r=0;r<4;r++){
        int l = strip + quad*4 + r;
        int d = nt*16 + lq;
        size_t gi = (size_t)(t0+l)*HDIM + d;
        h[gi] += acm[ntl][r] + mbl[d];
      }
    }
  } else {
    float ps[4] = {0.f,0.f,0.f,0.f};
#pragma unroll
    for(int ntl=0;ntl<2;ntl++){
      int nt = hgrp*2 + ntl;
      int d = nt*16 + lq;
      float wo = wout[d];
      float bias = mbl[d];
#pragma unroll
      for(int r=0;r<4;r++){
        int l = strip + quad*4 + r;
        size_t gi = (size_t)(t0+l)*HDIM + d;
        float hn = h[gi] + acm[ntl][r] + bias;
        ps[r] += hn * wo;
      }
    }
#pragma unroll
    for(int r=0;r<4;r++){
      ps[r] += __shfl_xor(ps[r],1); ps[r] += __shfl_xor(ps[r],2);
      ps[r] += __shfl_xor(ps[r],4); ps[r] += __shfl_xor(ps[r],8);
    }
    if(hgrp == 1 && lq == 0){
#pragma unroll
      for(int r=0;r<4;r++) outb[strip + quad*4 + r] = ps[r];
    }
    __syncthreads();
    if(hgrp == 0 && lq == 0){
#pragma unroll
      for(int r=0;r<4;r++){
        int l = strip + quad*4 + r;
        out[t0 + l] = ps[r] + outb[l];
      }
    }
  }
}

extern "C" void kernel_launch(void* const* d_in, const int* in_sizes, int n_in,
                              void* d_out, int out_size, void* d_ws, size_t ws_size,
                              hipStream_t stream){
  const float* x          = (const float*)d_in[0];
  const float* w_in       = (const float*)d_in[1];
  const float* w_out      = (const float*)d_in[2];
  const float* in_proj_w  = (const float*)d_in[3];
  const float* conv_w     = (const float*)d_in[4];
  const float* conv_b     = (const float*)d_in[5];
  const float* dt_bias    = (const float*)d_in[6];
  const float* A_log      = (const float*)d_in[7];
  const float* D_skip     = (const float*)d_in[8];
  const float* init_st    = (const float*)d_in[9];
  const float* norm_w     = (const float*)d_in[10];
  const float* out_proj_w = (const float*)d_in[11];
  const float* mlp_w      = (const float*)d_in[12];
  const float* mlp_b      = (const float*)d_in[13];
  float* out = (float*)d_out;

  float* ws = (float*)d_ws;
  float* h    = ws; ws += (size_t)NT*HDIM;
  unsigned short* zxz = (unsigned short*)ws; ws += (size_t)(128*NT)/2;   // bf16 z (channel-major)
  unsigned short* xbc = (unsigned short*)ws; ws += (size_t)(CDIM*NT)/2;  // bf16 conv out
  float* dt   = ws; ws += (size_t)NH*NT;
  float* acs  = ws; ws += (size_t)NH*NT;
  float* asum = ws; ws += (size_t)NB*NC*NH;                              // exp(chunk A-sum)
  float* S    = ws; ws += (size_t)NB*NC*NH*256;
  float* prev = ws; ws += (size_t)NB*NC*NH*256;
  unsigned short* whi = (unsigned short*)ws; ws += (size_t)(NBLK*EPROJ*HDIM)/2;
  unsigned short* wlo = (unsigned short*)ws; ws += (size_t)(NBLK*EPROJ*HDIM)/2;

  k_init<<<(NT*HDIM)/256 + (NBLK*EPROJ*HDIM)/256, 256, 0, stream>>>(x, w_in, h, in_proj_w, whi, wlo);
  for(int i=0;i<NBLK;i++){
    k_front<<<NB*NC, 1024, 0, stream>>>(h, whi + (size_t)i*EPROJ*HDIM, wlo + (size_t)i*EPROJ*HDIM,
                                        conv_w + i*CDIM*KCONV, conv_b + i*CDIM,
                                        dt_bias + i*NH, A_log + i*NH,
                                        zxz, xbc, dt, acs, asum, S);
    k_scan  <<<NB*NH*4, 64, 0, stream>>>(S, asum, init_st + i*NH*256, prev);
    k_tail  <<<NB*NC, 1024, 0, stream>>>(xbc, zxz, dt, acs, prev, D_skip + i*NH,
                                         norm_w + i*DIN, out_proj_w + i*HDIM*DIN,
                                         mlp_w + i*HDIM*HDIM, mlp_b + i*HDIM, h,
                                         (i == NBLK-1) ? 1 : 0, w_out, out);
  }
}